// Round 4
// baseline (78.626 us; speedup 1.0000x reference)
//
#include <hip/hip_runtime.h>
#include <math.h>

// Problem constants (from reference)
#define B 8
#define S 512
#define A 4
#define N (S*A)          // 2048 points per batch for the LJ term
#define SIGMA 3.0f
#define HB_R0 2.9f
#define HB_COEF (-12.5f) // -0.5 / 0.2^2
#define EPS 1e-6f

// ROUND JOURNAL:
//  r0 (split kernels, LDS j-tiles, 648 blocks): 70.6 us
//  r1 (fused, global-load j-tiles):             80.5 us  uniform global loads
//      don't scalarize; lost ds_read_b128 broadcast. REVERTED.
//  r2 (fused, LDS, __threadfence x648):         76.8 us  release fence =
//      buffer_wbl2 storm against poison-dirty L2s (~+6 us). REVERTED.
//  r3 (fused, LDS, fence-free sc0sc1 handoff):  72.0 us  fence theory
//      confirmed (-4.8); physics portion ~30 us in ALL variants.
//  r4 (this): OCCUPANCY. 648 blocks = 2.5 waves/SIMD for the whole kernel —
//      latency-bound (ds_read chain ~120cy, nothing to hide it). Halve j-tile
//      width: 1152 LJ + 128 HB + 8 aux = 1288 blocks = ~5 waves/SIMD.
//      Same pair-work, same math, same handoff.
//
// Block roles (1D grid, single fused kernel):
//   [0, NLJ)            LJ: 8 batches x 36 tile-pairs(it<=jt) x 4 j-quarters(64)
//   [NLJ, NLJ+NHB)      HB: 8 batches x 2 i-tiles(256) x 8 j-eighths(64)
//   [NLJ+NHB, +NAUX)    per-batch aux moments (Rg, motor, mask sums)
#define NLJ 1152
#define NHB 128
#define NAUX 8
#define NBLOCKS (NLJ + NHB + NAUX)

// ws layout (floats) — every slot read by the finisher is written by exactly
// one block this iteration, so no zero-init needed:
//   [0, 1152)        LJ partial numerators
//   [1152, 1280)     HB partial numerators
//   [1280 + b*8 + k) aux: S1x,S1y,S1z,S2,M,Sm2,motor_num,motor_den
#define WS_LJ  0
#define WS_HB  1152
#define WS_AUX 1280

// Monotonic ticket (device global, survives the harness ws re-poison).
// Every launch adds exactly NBLOCKS, so (old % NBLOCKS == NBLOCKS-1)
// identifies the last arrival of ANY launch (incl. graph replays).
__device__ unsigned long long g_ticket = 0ull;

// Coherent-point accessors: relaxed agent-scope atomics compile to
// global_store/load with sc0 sc1 — visible across XCDs without fences.
__device__ __forceinline__ void ws_store(float* p, float v) {
    __hip_atomic_store(p, v, __ATOMIC_RELAXED, __HIP_MEMORY_SCOPE_AGENT);
}
__device__ __forceinline__ float ws_load(const float* p) {
    return __hip_atomic_load(p, __ATOMIC_RELAXED, __HIP_MEMORY_SCOPE_AGENT);
}

__device__ __forceinline__ float wave_reduce_sum(float v) {
    #pragma unroll
    for (int off = 32; off > 0; off >>= 1) v += __shfl_down(v, off, 64);
    return v;
}

__global__ __launch_bounds__(256) void physics_fused(
        const float* __restrict__ coords,
        const float* __restrict__ motors,
        const float* __restrict__ mask,
        float* __restrict__ ws,
        float* __restrict__ out) {
    const int bid = blockIdx.x;
    const int tid = threadIdx.x;
    const int wid = tid >> 6, lane = tid & 63;

    __shared__ float4 sj[64];      // staged j-points: (x,y,z,mask) — broadcast
                                   // ds_read_b128 reads are conflict-free
    __shared__ float  redbuf[32];  // 4 waves x up to 8 values
    __shared__ int    slast;

    if (bid < NLJ) {
        // ---------------- LJ clash (symmetric tiles, 64-wide j) ----------------
        const int b  = bid / 144;
        const int r  = bid % 144;
        const int p  = r >> 2;          // tile-pair index in upper triangle
        const int qh = r & 3;           // which 64-wide j quarter
        int it = 0, pp = p;
        while (pp >= 8 - it) { pp -= 8 - it; ++it; }
        const int jt = it + pp;         // it <= jt

        const float* cb = coords + (size_t)b * N * 3;
        const float* mb = mask + b * S;
        const int jlo = jt * 256 + qh * 64;

        if (tid < 64) {
            const int j = jlo + tid;
            sj[tid] = make_float4(cb[j*3+0], cb[j*3+1], cb[j*3+2], mb[j >> 2]);
        }
        __syncthreads();

        const int i = it * 256 + tid;
        const float xi = cb[i*3+0], yi = cb[i*3+1], zi = cb[i*3+2];
        const float fmi = mb[i >> 2];

        float acc = 0.f;
        #pragma unroll 8
        for (int jj = 0; jj < 64; ++jj) {
            const float4 q = sj[jj];
            const float dx = xi - q.x;
            const float dy = yi - q.y;
            const float dz = zi - q.z;
            const float d2 = fmaf(dx, dx, fmaf(dy, dy, fmaf(dz, dz, EPS)));
            const float rr = __builtin_amdgcn_sqrtf(d2);
            const float ov = fmaxf(SIGMA - rr, 0.f);
            const float ov2 = ov * ov;
            acc = fmaf(ov2 * ov2, q.w, acc);
        }
        // remove i==j (only possible in diagonal tiles); bit-identical expr
        if (it == jt && i >= jlo && i < jlo + 64) {
            const float ovd = SIGMA - __builtin_amdgcn_sqrtf(EPS);
            const float o2 = ovd * ovd;
            acc -= fmi * (o2 * o2);
        }
        float v = fmi * acc;
        if (it != jt) v *= 2.f;          // count (j,i) pairs too

        v = wave_reduce_sum(v);
        if (lane == 0) redbuf[wid] = v;
        __syncthreads();
        if (tid == 0)
            ws_store(&ws[WS_LJ + bid], redbuf[0] + redbuf[1] + redbuf[2] + redbuf[3]);

    } else if (bid < NLJ + NHB) {
        // ---------------- H-bond term (64-wide j) ----------------
        const int idx = bid - NLJ;      // [0, 128)
        const int b   = idx >> 4;
        const int r16 = idx & 15;
        const int it  = r16 >> 3;       // 0..1 (i tiles of 256)
        const int j8  = r16 & 7;        // 0..7 (j eighths of 64)

        const float* cb = coords + (size_t)b * S * A * 3;
        const float* mb = mask + b * S;
        const int jlo = j8 * 64;

        if (tid < 64) {
            const int j = jlo + tid;    // Oc = atom 3
            sj[tid] = make_float4(cb[(j*4+3)*3+0], cb[(j*4+3)*3+1],
                                  cb[(j*4+3)*3+2], mb[j]);
        }
        __syncthreads();

        const int i = it * 256 + tid;   // Nc = atom 0
        const float xi = cb[(i*4+0)*3+0];
        const float yi = cb[(i*4+0)*3+1];
        const float zi = cb[(i*4+0)*3+2];
        const float mi = mb[i];

        float acc = 0.f;
        #pragma unroll 8
        for (int jj = 0; jj < 64; ++jj) {
            const float4 q = sj[jj];
            const float dx = xi - q.x;
            const float dy = yi - q.y;
            const float dz = zi - q.z;
            const float d2 = fmaf(dx, dx, fmaf(dy, dy, dz * dz)); // no EPS (ref)
            const float dist = __builtin_amdgcn_sqrtf(d2);
            const float t = dist - HB_R0;
            const float e = __expf(HB_COEF * (t * t));
            acc = fmaf(e, q.w, acc);
        }
        // subtract the |i-j| <= 2 band (range_mask==0 there); same LDS values
        // -> bit-identical -> exact cancellation
        #pragma unroll
        for (int dj = -2; dj <= 2; ++dj) {
            const int j = i + dj;
            if (j >= jlo && j < jlo + 64) {
                const float4 q = sj[j - jlo];
                const float dx = xi - q.x;
                const float dy = yi - q.y;
                const float dz = zi - q.z;
                const float d2 = fmaf(dx, dx, fmaf(dy, dy, dz * dz));
                const float dist = __builtin_amdgcn_sqrtf(d2);
                const float t = dist - HB_R0;
                const float e = __expf(HB_COEF * (t * t));
                acc -= e * q.w;
            }
        }
        float v = mi * acc;
        v = wave_reduce_sum(v);
        if (lane == 0) redbuf[wid] = v;
        __syncthreads();
        if (tid == 0)
            ws_store(&ws[WS_HB + idx], redbuf[0] + redbuf[1] + redbuf[2] + redbuf[3]);

    } else {
        // ---------------- aux: Rg moments, motor smoothness, mask sums ----------------
        const int b = bid - NLJ - NHB;
        const float* cb = coords + (size_t)b * S * A * 3;
        const float* mb = mask + b * S;

        float s1x = 0.f, s1y = 0.f, s1z = 0.f, s2 = 0.f, M = 0.f, Sm2 = 0.f;
        float mn = 0.f, md = 0.f;

        for (int s = tid; s < S; s += 256) {
            const float m = mb[s];
            const float* ca = cb + ((size_t)(s*4 + 1)) * 3;   // atom 1
            const float x = ca[0], y = ca[1], z = ca[2];
            s1x = fmaf(x, m, s1x);
            s1y = fmaf(y, m, s1y);
            s1z = fmaf(z, m, s1z);
            s2  = fmaf(fmaf(x, x, fmaf(y, y, z * z)), m, s2);
            M   += m;
            Sm2 = fmaf(m, m, Sm2);
            if (s < S - 1) {
                const float mm = m * mb[s + 1];
                const float4* m4 = (const float4*)(motors + ((size_t)b * S + s) * 8);
                const float4 a0 = m4[0], a1 = m4[1], b0 = m4[2], b1 = m4[3];
                float d = 0.f;
                float df;
                df = b0.x - a0.x; d = fmaf(df, df, d);
                df = b0.y - a0.y; d = fmaf(df, df, d);
                df = b0.z - a0.z; d = fmaf(df, df, d);
                df = b0.w - a0.w; d = fmaf(df, df, d);
                df = b1.x - a1.x; d = fmaf(df, df, d);
                df = b1.y - a1.y; d = fmaf(df, df, d);
                df = b1.z - a1.z; d = fmaf(df, df, d);
                df = b1.w - a1.w; d = fmaf(df, df, d);
                mn = fmaf(d, mm, mn);
                md += mm;
            }
        }

        float vals[8] = {s1x, s1y, s1z, s2, M, Sm2, mn, md};
        #pragma unroll
        for (int k = 0; k < 8; ++k) {
            float v = wave_reduce_sum(vals[k]);
            if (lane == 0) redbuf[wid * 8 + k] = v;
        }
        __syncthreads();
        if (tid < 8) {
            const float t = redbuf[tid] + redbuf[8 + tid] + redbuf[16 + tid] + redbuf[24 + tid];
            ws_store(&ws[WS_AUX + b * 8 + tid], t);
        }
    }

    // ---------------- fence-free last-block-done reduction ----------------
    // All of this block's ws stores were issued by wave 0 (tid==0 or tid<8).
    // Wave-0 program order + vmcnt(0) drains those sc1 stores to the coherent
    // point BEFORE the ticket RMW (also at the coherent point) — no wbl2.
    if (tid == 0) {
        asm volatile("s_waitcnt vmcnt(0)" ::: "memory");
        const unsigned long long t =
            __hip_atomic_fetch_add(&g_ticket, 1ull, __ATOMIC_RELAXED,
                                   __HIP_MEMORY_SCOPE_AGENT);
        slast = ((int)(t % (unsigned long long)NBLOCKS) == NBLOCKS - 1) ? 1 : 0;
    }
    __syncthreads();
    if (slast) {
        // Reads bypass this XCD's (possibly stale) L1/L2 via sc0 sc1.
        float lj = 0.f;
        for (int k = tid; k < NLJ; k += 256) lj += ws_load(&ws[WS_LJ + k]);
        float hb = (tid < NHB) ? ws_load(&ws[WS_HB + tid]) : 0.f;

        lj = wave_reduce_sum(lj);
        hb = wave_reduce_sum(hb);
        if (lane == 0) { redbuf[wid * 2 + 0] = lj; redbuf[wid * 2 + 1] = hb; }
        __syncthreads();

        if (tid == 0) {
            const float lj_num = redbuf[0] + redbuf[2] + redbuf[4] + redbuf[6];
            const float hb_num = redbuf[1] + redbuf[3] + redbuf[5] + redbuf[7];

            float lj_den = 0.f, masksum = 0.f, mnum = 0.f, mden = 0.f, rg = 0.f;
            #pragma unroll
            for (int b = 0; b < B; ++b) {
                const float* p = ws + WS_AUX + b * 8;
                float pv[8];
                #pragma unroll
                for (int k = 0; k < 8; ++k) pv[k] = ws_load(&p[k]);
                const float M = pv[4], Sm2 = pv[5];
                lj_den  += 16.f * M * M - 4.f * Sm2;   // sum pair_mask, analytic
                masksum += M;
                mnum    += pv[6];
                mden    += pv[7];
                const float Me = M + EPS;
                const float mx = pv[0] / Me, my = pv[1] / Me, mz = pv[2] / Me;
                // sum m*|ca-mean|^2 = S2 - 2 mean.S1 + |mean|^2 * M
                const float d2sum = pv[3] - 2.f * (mx * pv[0] + my * pv[1] + mz * pv[2])
                                  + (mx * mx + my * my + mz * mz) * M;
                rg += d2sum / Me;
            }
            rg *= (1.f / (float)B);

            const float ljv   = lj_num / (lj_den + EPS);
            const float hbv   = -hb_num / (masksum + EPS);
            const float motor = mnum / (mden + EPS);
            out[0] = ljv + 0.5f * hbv + 0.1f * motor + 0.05f * rg;
        }
    }
}

extern "C" void kernel_launch(void* const* d_in, const int* in_sizes, int n_in,
                              void* d_out, int out_size, void* d_ws, size_t ws_size,
                              hipStream_t stream) {
    const float* coords = (const float*)d_in[0];
    const float* motors = (const float*)d_in[1];
    const float* mask   = (const float*)d_in[2];
    float* ws  = (float*)d_ws;
    float* out = (float*)d_out;

    physics_fused<<<NBLOCKS, 256, 0, stream>>>(coords, motors, mask, ws, out);
}

// Round 5
// 71.443 us; speedup vs baseline: 1.1005x; 1.1005x over previous
//
#include <hip/hip_runtime.h>
#include <math.h>

// Problem constants (from reference)
#define B 8
#define S 512
#define A 4
#define N (S*A)          // 2048 points per batch for the LJ term
#define SIGMA 3.0f
#define HB_R0 2.9f
#define HB_COEF (-12.5f) // -0.5 / 0.2^2
#define EPS 1e-6f

// ROUND JOURNAL:
//  r0 (split kernels, LDS j-tiles, 648 blocks): 70.6 us
//  r1 (fused, global-load j-tiles):             80.5 us  uniform global loads
//      don't scalarize. REVERTED.
//  r2 (fused, LDS, __threadfence x648):         76.8 us  buffer_wbl2 storm
//      against poison-dirty L2s. REVERTED.
//  r3 (fused, LDS, fence-free sc0sc1 handoff):  72.0 us  fence theory ok, but
//      fusion still doesn't beat split.
//  r4 (1288 blocks, 64-wide j):                 78.6 us  OCCUPANCY THEORY
//      FALSIFIED: more blocks = worse. Per-block cost scales with grid; prime
//      suspect = 648..1288 same-address ticket RMWs serializing at the
//      coherent point (~30-60 cyc each) = 5-16 us tail. REVERTED to 648.
//  r5 (this): hierarchical arrival. 648 = 8 groups x 81 blocks; per-group
//      counters on separate 128B lines (8 parallel queues, ~81 deep) + an
//      8-deep super counter. Everything else identical to r3.
//
// Block roles (1D grid, single fused kernel):
//   [0, NLJ)            LJ: 8 batches x 36 tile-pairs(it<=jt) x 2 j-halves(128)
//   [NLJ, NLJ+NHB)      HB: 8 batches x 2 i-tiles(256) x 4 j-quarters(128)
//   [NLJ+NHB, +NAUX)    per-batch aux moments (Rg, motor, mask sums)
#define NLJ 576
#define NHB 64
#define NAUX 8
#define NBLOCKS (NLJ + NHB + NAUX)   // 648 = 8 * 81 exactly
#define GRP_SIZE 81
#define NGRP 8

// ws layout (floats) — every slot read by the finisher is written by exactly
// one block this iteration, so no zero-init needed:
//   [0, 576)        LJ partial numerators
//   [576, 640)      HB partial numerators
//   [640 + b*8 + k) aux: S1x,S1y,S1z,S2,M,Sm2,motor_num,motor_den
#define WS_LJ  0
#define WS_HB  576
#define WS_AUX 640

// Hierarchical monotonic tickets (device globals, zero-init, survive the ws
// re-poison). Every launch adds exactly GRP_SIZE per group counter and NGRP to
// the super counter, so modulo tests identify last arrivals of ANY launch
// (incl. rocprof counter-group replays). Counters sit 128 B apart -> each gets
// its own L2 line -> 8 parallel RMW queues instead of one 648-deep queue.
__device__ unsigned long long g_gtick[NGRP * 16];
__device__ unsigned long long g_super[16];

// Coherent-point accessors: relaxed agent-scope atomics compile to
// global_store/load with sc0 sc1 — visible across XCDs without fences.
__device__ __forceinline__ void ws_store(float* p, float v) {
    __hip_atomic_store(p, v, __ATOMIC_RELAXED, __HIP_MEMORY_SCOPE_AGENT);
}
__device__ __forceinline__ float ws_load(const float* p) {
    return __hip_atomic_load(p, __ATOMIC_RELAXED, __HIP_MEMORY_SCOPE_AGENT);
}

__device__ __forceinline__ float wave_reduce_sum(float v) {
    #pragma unroll
    for (int off = 32; off > 0; off >>= 1) v += __shfl_down(v, off, 64);
    return v;
}

__global__ __launch_bounds__(256) void physics_fused(
        const float* __restrict__ coords,
        const float* __restrict__ motors,
        const float* __restrict__ mask,
        float* __restrict__ ws,
        float* __restrict__ out) {
    const int bid = blockIdx.x;
    const int tid = threadIdx.x;
    const int wid = tid >> 6, lane = tid & 63;

    __shared__ float4 sj[128];     // staged j-points: (x,y,z,mask) — broadcast
                                   // ds_read_b128 reads are conflict-free
    __shared__ float  redbuf[32];  // 4 waves x up to 8 values
    __shared__ int    slast;

    if (bid < NLJ) {
        // ---------------- LJ clash (symmetric tiles) ----------------
        const int b    = bid / 72;
        const int r    = bid % 72;
        const int p    = r >> 1;        // tile-pair index in upper triangle
        const int half = r & 1;         // which 128-wide j half
        int it = 0, pp = p;
        while (pp >= 8 - it) { pp -= 8 - it; ++it; }
        const int jt = it + pp;         // it <= jt

        const float* cb = coords + (size_t)b * N * 3;
        const float* mb = mask + b * S;
        const int jlo = jt * 256 + half * 128;

        if (tid < 128) {
            const int j = jlo + tid;
            sj[tid] = make_float4(cb[j*3+0], cb[j*3+1], cb[j*3+2], mb[j >> 2]);
        }
        __syncthreads();

        const int i = it * 256 + tid;
        const float xi = cb[i*3+0], yi = cb[i*3+1], zi = cb[i*3+2];
        const float fmi = mb[i >> 2];

        float acc = 0.f;
        #pragma unroll 8
        for (int jj = 0; jj < 128; ++jj) {
            const float4 q = sj[jj];
            const float dx = xi - q.x;
            const float dy = yi - q.y;
            const float dz = zi - q.z;
            const float d2 = fmaf(dx, dx, fmaf(dy, dy, fmaf(dz, dz, EPS)));
            const float rr = __builtin_amdgcn_sqrtf(d2);
            const float ov = fmaxf(SIGMA - rr, 0.f);
            const float ov2 = ov * ov;
            acc = fmaf(ov2 * ov2, q.w, acc);
        }
        // remove i==j (only possible in diagonal tiles); bit-identical expr
        if (it == jt && i >= jlo && i < jlo + 128) {
            const float ovd = SIGMA - __builtin_amdgcn_sqrtf(EPS);
            const float o2 = ovd * ovd;
            acc -= fmi * (o2 * o2);
        }
        float v = fmi * acc;
        if (it != jt) v *= 2.f;          // count (j,i) pairs too

        v = wave_reduce_sum(v);
        if (lane == 0) redbuf[wid] = v;
        __syncthreads();
        if (tid == 0)
            ws_store(&ws[WS_LJ + bid], redbuf[0] + redbuf[1] + redbuf[2] + redbuf[3]);

    } else if (bid < NLJ + NHB) {
        // ---------------- H-bond term ----------------
        const int idx = bid - NLJ;      // [0, 64)
        const int b  = idx >> 3;
        const int r8 = idx & 7;
        const int it = r8 >> 2;         // 0..1 (i tiles of 256)
        const int jh = r8 & 3;          // 0..3 (j quarters of 128)

        const float* cb = coords + (size_t)b * S * A * 3;
        const float* mb = mask + b * S;
        const int jlo = jh * 128;

        if (tid < 128) {
            const int j = jlo + tid;    // Oc = atom 3
            sj[tid] = make_float4(cb[(j*4+3)*3+0], cb[(j*4+3)*3+1],
                                  cb[(j*4+3)*3+2], mb[j]);
        }
        __syncthreads();

        const int i = it * 256 + tid;   // Nc = atom 0
        const float xi = cb[(i*4+0)*3+0];
        const float yi = cb[(i*4+0)*3+1];
        const float zi = cb[(i*4+0)*3+2];
        const float mi = mb[i];

        float acc = 0.f;
        #pragma unroll 8
        for (int jj = 0; jj < 128; ++jj) {
            const float4 q = sj[jj];
            const float dx = xi - q.x;
            const float dy = yi - q.y;
            const float dz = zi - q.z;
            const float d2 = fmaf(dx, dx, fmaf(dy, dy, dz * dz)); // no EPS (ref)
            const float dist = __builtin_amdgcn_sqrtf(d2);
            const float t = dist - HB_R0;
            const float e = __expf(HB_COEF * (t * t));
            acc = fmaf(e, q.w, acc);
        }
        // subtract the |i-j| <= 2 band (range_mask==0 there); same LDS values
        // -> bit-identical -> exact cancellation
        #pragma unroll
        for (int dj = -2; dj <= 2; ++dj) {
            const int j = i + dj;
            if (j >= jlo && j < jlo + 128) {
                const float4 q = sj[j - jlo];
                const float dx = xi - q.x;
                const float dy = yi - q.y;
                const float dz = zi - q.z;
                const float d2 = fmaf(dx, dx, fmaf(dy, dy, dz * dz));
                const float dist = __builtin_amdgcn_sqrtf(d2);
                const float t = dist - HB_R0;
                const float e = __expf(HB_COEF * (t * t));
                acc -= e * q.w;
            }
        }
        float v = mi * acc;
        v = wave_reduce_sum(v);
        if (lane == 0) redbuf[wid] = v;
        __syncthreads();
        if (tid == 0)
            ws_store(&ws[WS_HB + idx], redbuf[0] + redbuf[1] + redbuf[2] + redbuf[3]);

    } else {
        // ---------------- aux: Rg moments, motor smoothness, mask sums ----------------
        const int b = bid - NLJ - NHB;
        const float* cb = coords + (size_t)b * S * A * 3;
        const float* mb = mask + b * S;

        float s1x = 0.f, s1y = 0.f, s1z = 0.f, s2 = 0.f, M = 0.f, Sm2 = 0.f;
        float mn = 0.f, md = 0.f;

        for (int s = tid; s < S; s += 256) {
            const float m = mb[s];
            const float* ca = cb + ((size_t)(s*4 + 1)) * 3;   // atom 1
            const float x = ca[0], y = ca[1], z = ca[2];
            s1x = fmaf(x, m, s1x);
            s1y = fmaf(y, m, s1y);
            s1z = fmaf(z, m, s1z);
            s2  = fmaf(fmaf(x, x, fmaf(y, y, z * z)), m, s2);
            M   += m;
            Sm2 = fmaf(m, m, Sm2);
            if (s < S - 1) {
                const float mm = m * mb[s + 1];
                const float4* m4 = (const float4*)(motors + ((size_t)b * S + s) * 8);
                const float4 a0 = m4[0], a1 = m4[1], b0 = m4[2], b1 = m4[3];
                float d = 0.f;
                float df;
                df = b0.x - a0.x; d = fmaf(df, df, d);
                df = b0.y - a0.y; d = fmaf(df, df, d);
                df = b0.z - a0.z; d = fmaf(df, df, d);
                df = b0.w - a0.w; d = fmaf(df, df, d);
                df = b1.x - a1.x; d = fmaf(df, df, d);
                df = b1.y - a1.y; d = fmaf(df, df, d);
                df = b1.z - a1.z; d = fmaf(df, df, d);
                df = b1.w - a1.w; d = fmaf(df, df, d);
                mn = fmaf(d, mm, mn);
                md += mm;
            }
        }

        float vals[8] = {s1x, s1y, s1z, s2, M, Sm2, mn, md};
        #pragma unroll
        for (int k = 0; k < 8; ++k) {
            float v = wave_reduce_sum(vals[k]);
            if (lane == 0) redbuf[wid * 8 + k] = v;
        }
        __syncthreads();
        if (tid < 8) {
            const float t = redbuf[tid] + redbuf[8 + tid] + redbuf[16 + tid] + redbuf[24 + tid];
            ws_store(&ws[WS_AUX + b * 8 + tid], t);
        }
    }

    // ---------------- hierarchical fence-free last-block reduction ----------------
    // Each block: drain its sc1 ws stores (wave-0 issued them all), then one
    // RMW on its group counter. Group-completing block does one super RMW.
    // Visibility chain: ws stores -> vmcnt(0) -> group RMW -> (dep) super RMW;
    // finisher reads ws with sc0 sc1 (bypasses stale L1/L2). No wbl2 anywhere.
    if (tid == 0) {
        asm volatile("s_waitcnt vmcnt(0)" ::: "memory");
        const int g = bid / GRP_SIZE;          // 8 groups of exactly 81
        const unsigned long long t =
            __hip_atomic_fetch_add(&g_gtick[g * 16], 1ull, __ATOMIC_RELAXED,
                                   __HIP_MEMORY_SCOPE_AGENT);
        int lastflag = 0;
        if ((int)(t % (unsigned long long)GRP_SIZE) == GRP_SIZE - 1) {
            const unsigned long long s =
                __hip_atomic_fetch_add(&g_super[0], 1ull, __ATOMIC_RELAXED,
                                       __HIP_MEMORY_SCOPE_AGENT);
            lastflag = ((int)(s % (unsigned long long)NGRP) == NGRP - 1) ? 1 : 0;
        }
        slast = lastflag;
    }
    __syncthreads();
    if (slast) {
        float lj = 0.f;
        for (int k = tid; k < NLJ; k += 256) lj += ws_load(&ws[WS_LJ + k]);
        float hb = (tid < NHB) ? ws_load(&ws[WS_HB + tid]) : 0.f;

        lj = wave_reduce_sum(lj);
        hb = wave_reduce_sum(hb);
        if (lane == 0) { redbuf[wid * 2 + 0] = lj; redbuf[wid * 2 + 1] = hb; }
        __syncthreads();

        if (tid == 0) {
            const float lj_num = redbuf[0] + redbuf[2] + redbuf[4] + redbuf[6];
            const float hb_num = redbuf[1] + redbuf[3] + redbuf[5] + redbuf[7];

            float lj_den = 0.f, masksum = 0.f, mnum = 0.f, mden = 0.f, rg = 0.f;
            #pragma unroll
            for (int b = 0; b < B; ++b) {
                const float* p = ws + WS_AUX + b * 8;
                float pv[8];
                #pragma unroll
                for (int k = 0; k < 8; ++k) pv[k] = ws_load(&p[k]);
                const float M = pv[4], Sm2 = pv[5];
                lj_den  += 16.f * M * M - 4.f * Sm2;   // sum pair_mask, analytic
                masksum += M;
                mnum    += pv[6];
                mden    += pv[7];
                const float Me = M + EPS;
                const float mx = pv[0] / Me, my = pv[1] / Me, mz = pv[2] / Me;
                // sum m*|ca-mean|^2 = S2 - 2 mean.S1 + |mean|^2 * M
                const float d2sum = pv[3] - 2.f * (mx * pv[0] + my * pv[1] + mz * pv[2])
                                  + (mx * mx + my * my + mz * mz) * M;
                rg += d2sum / Me;
            }
            rg *= (1.f / (float)B);

            const float ljv   = lj_num / (lj_den + EPS);
            const float hbv   = -hb_num / (masksum + EPS);
            const float motor = mnum / (mden + EPS);
            out[0] = ljv + 0.5f * hbv + 0.1f * motor + 0.05f * rg;
        }
    }
}

extern "C" void kernel_launch(void* const* d_in, const int* in_sizes, int n_in,
                              void* d_out, int out_size, void* d_ws, size_t ws_size,
                              hipStream_t stream) {
    const float* coords = (const float*)d_in[0];
    const float* motors = (const float*)d_in[1];
    const float* mask   = (const float*)d_in[2];
    float* ws  = (float*)d_ws;
    float* out = (float*)d_out;

    physics_fused<<<NBLOCKS, 256, 0, stream>>>(coords, motors, mask, ws, out);
}